// Round 1
// baseline (144.887 us; speedup 1.0000x reference)
//
#include <hip/hip_runtime.h>
#include <hip/hip_bf16.h>
#include <stdint.h>

#define HID 160
#define HID4 640
#define FDIM 32
#define NPIX 1024

// Gaussian blur taps: e = exp(-0.5); k = [e,1,e]/(1+2e)
#define GK0 0.27406862f
#define GK1 0.45186276f

typedef __attribute__((ext_vector_type(8))) short short8;
typedef __attribute__((ext_vector_type(4))) float f32x4;

__device__ __forceinline__ ushort f2b(float f) {
  union { float f; uint32_t u; } v; v.f = f;
  uint32_t u = v.u;
  u += 0x7fffu + ((u >> 16) & 1u);   // RNE
  return (ushort)(u >> 16);
}
__device__ __forceinline__ float b2f(ushort s) {
  union { uint32_t u; float f; } v; v.u = ((uint32_t)s) << 16;
  return v.f;
}

// ------------------------------------------------------------------
// K1: per-sample attn processing: mean over Q, blur, argmax (norm is
// argmax-invariant so skipped), sigmoid row/col sums -> prepos/presize
// ------------------------------------------------------------------
__global__ __launch_bounds__(256) void attn_kernel(const float* __restrict__ attn,
                                                   float* __restrict__ pp) {
  const int n = blockIdx.x;
  const int tid = threadIdx.x;
  __shared__ float am[FDIM][FDIM + 1];
  __shared__ float tmp[FDIM][FDIM + 1];
  __shared__ float bl[FDIM][FDIM + 1];
  __shared__ float rowsum[FDIM], colsum[FDIM];
  __shared__ float redv[4];
  __shared__ int redi[4];

  const float* base = attn + (size_t)n * (16 * NPIX);
  float4 a = make_float4(0.f, 0.f, 0.f, 0.f);
#pragma unroll
  for (int q = 0; q < 16; ++q) {
    float4 v = *(const float4*)(base + q * NPIX + tid * 4);
    a.x += v.x; a.y += v.y; a.z += v.z; a.w += v.w;
  }
  {
    const int f0 = tid * 4;
    const int r = f0 >> 5, c = f0 & 31;
    am[r][c + 0] = a.x * 0.0625f;
    am[r][c + 1] = a.y * 0.0625f;
    am[r][c + 2] = a.z * 0.0625f;
    am[r][c + 3] = a.w * 0.0625f;
  }
  __syncthreads();
  // vertical blur (reflect)
  for (int f = tid; f < NPIX; f += 256) {
    int r = f >> 5, c = f & 31;
    int rm = (r == 0) ? 1 : r - 1;
    int rp = (r == 31) ? 30 : r + 1;
    tmp[r][c] = GK0 * am[rm][c] + GK1 * am[r][c] + GK0 * am[rp][c];
  }
  __syncthreads();
  // horizontal blur (reflect)
  for (int f = tid; f < NPIX; f += 256) {
    int r = f >> 5, c = f & 31;
    int cm = (c == 0) ? 1 : c - 1;
    int cp = (c == 31) ? 30 : c + 1;
    bl[r][c] = GK0 * tmp[r][cm] + GK1 * tmp[r][c] + GK0 * tmp[r][cp];
  }
  __syncthreads();
  // argmax over blurred map (first occurrence on ties)
  float bv = -1e30f; int bi = 0;
  for (int f = tid; f < NPIX; f += 256) {
    float v = bl[f >> 5][f & 31];
    if (v > bv || (v == bv && f < bi)) { bv = v; bi = f; }
  }
  for (int off = 32; off > 0; off >>= 1) {
    float ov = __shfl_down(bv, off);
    int oi = __shfl_down(bi, off);
    if (ov > bv || (ov == bv && oi < bi)) { bv = ov; bi = oi; }
  }
  if ((tid & 63) == 0) { redv[tid >> 6] = bv; redi[tid >> 6] = bi; }
  // sigmoid (clipped) into tmp
  for (int f = tid; f < NPIX; f += 256) {
    int r = f >> 5, c = f & 31;
    float s = 1.f / (1.f + expf(-am[r][c]));
    tmp[r][c] = fminf(fmaxf(s, 1e-4f), 0.9999f);
  }
  __syncthreads();
  if (tid < 32) {
    float s = 0.f;
    for (int c = 0; c < 32; ++c) s += tmp[tid][c];
    rowsum[tid] = s;
  } else if (tid < 64) {
    int c = tid - 32;
    float s = 0.f;
    for (int r = 0; r < 32; ++r) s += tmp[r][c];
    colsum[c] = s;
  }
  __syncthreads();
  if (tid == 0) {
    float bestv = redv[0]; int besti = redi[0];
    for (int w = 1; w < 4; ++w)
      if (redv[w] > bestv || (redv[w] == bestv && redi[w] < besti)) {
        bestv = redv[w]; besti = redi[w];
      }
    int px = besti & 31, py = besti >> 5;
    int c0 = max(0, px - 3), c1 = min(32, px + 3);
    float sx = 0.f;
    for (int c = c0; c < c1; ++c) sx += colsum[c];
    float psx = (sx / (32.f * (float)(c1 - c0))) * 32.f;
    int r0 = max(0, py - 3), r1 = min(32, py + 3);
    float sy = 0.f;
    for (int r = r0; r < r1; ++r) sy += rowsum[r];
    float psy = (sy / (32.f * (float)(r1 - r0))) * 32.f;
    pp[n * 4 + 0] = (float)px;
    pp[n * 4 + 1] = (float)py;
    pp[n * 4 + 2] = psx;
    pp[n * 4 + 3] = psy;
  }
}

// ------------------------------------------------------------------
// K2: mean over Q for query_embedding & feature_pos, cast to bf16
// ------------------------------------------------------------------
__global__ __launch_bounds__(256) void mean_kernel(const float* __restrict__ qemb,
                                                   const float* __restrict__ fpos,
                                                   ushort* __restrict__ qe_b,
                                                   ushort* __restrict__ fp_b,
                                                   int total) {
  int idx = blockIdx.x * 256 + threadIdx.x;
  if (idx >= 2 * total) return;
  const float* src; ushort* dst; int i;
  if (idx < total) { src = qemb; dst = qe_b; i = idx; }
  else             { src = fpos; dst = fp_b; i = idx - total; }
  int nn = i / HID, h = i - nn * HID;
  const float* p = src + (size_t)nn * (16 * HID) + h;
  float s = 0.f;
#pragma unroll
  for (int q = 0; q < 16; ++q) s += p[q * HID];
  dst[i] = f2b(s * 0.0625f);
}

// ------------------------------------------------------------------
// K3: transpose [K,640] f32 -> [640,K] bf16 (so GEMM B reads are
// contiguous along K in LDS)
// ------------------------------------------------------------------
__global__ __launch_bounds__(256) void transpose_cast(const float* __restrict__ in,
                                                      ushort* __restrict__ out, int K) {
  __shared__ float t[32][33];
  const int bx = blockIdx.x * 32;  // n base
  const int by = blockIdx.y * 32;  // k base
  const int lx = threadIdx.x;
  const int ly = threadIdx.y;
#pragma unroll
  for (int i = 0; i < 4; ++i)
    t[ly + i * 8][lx] = in[(size_t)(by + ly + i * 8) * HID4 + bx + lx];
  __syncthreads();
#pragma unroll
  for (int i = 0; i < 4; ++i)
    out[(size_t)(bx + ly + i * 8) * K + by + lx] = f2b(t[lx][ly + i * 8]);
}

// ------------------------------------------------------------------
// K4-6: 64x64-tile bf16 MFMA GEMM, fused bias + ReLU, bf16 output.
// A [M,K] bf16, W [640,K] bf16 (pre-transposed), grid.z selects chain.
// ------------------------------------------------------------------
template <int K>
__global__ __launch_bounds__(256) void gemm_relu(
    const ushort* __restrict__ A0, const ushort* __restrict__ A1,
    const ushort* __restrict__ W0, const ushort* __restrict__ W1,
    const float* __restrict__ B0, const float* __restrict__ B1,
    ushort* __restrict__ O0, ushort* __restrict__ O1) {
  const int chain = blockIdx.z;
  const ushort* A = chain ? A1 : A0;
  const ushort* W = chain ? W1 : W0;
  const float* bias = chain ? B1 : B0;
  ushort* O = chain ? O1 : O0;

  __shared__ ushort la[64][40];  // +8 pad: 80B row stride, 16B aligned
  __shared__ ushort lb[64][40];

  const int tid = threadIdx.x;
  const int bm = blockIdx.y * 64;
  const int bn = blockIdx.x * 64;
  const int lane = tid & 63;
  const int wid = tid >> 6;
  const int wr = (wid >> 1) * 32;
  const int wc = (wid & 1) * 32;
  const int srow = tid >> 2;        // 0..63
  const int sseg = (tid & 3) * 8;   // 0,8,16,24
  const int l15 = lane & 15;
  const int kq = (lane >> 4) * 8;

  f32x4 acc[2][2] = {};
  for (int k0 = 0; k0 < K; k0 += 32) {
    uint4 av = *(const uint4*)(A + (size_t)(bm + srow) * K + k0 + sseg);
    uint4 wv = *(const uint4*)(W + (size_t)(bn + srow) * K + k0 + sseg);
    __syncthreads();
    *(uint4*)(&la[srow][sseg]) = av;
    *(uint4*)(&lb[srow][sseg]) = wv;
    __syncthreads();
    short8 af0 = *(const short8*)(&la[wr + l15][kq]);
    short8 af1 = *(const short8*)(&la[wr + 16 + l15][kq]);
    short8 bf0 = *(const short8*)(&lb[wc + l15][kq]);
    short8 bf1 = *(const short8*)(&lb[wc + 16 + l15][kq]);
    acc[0][0] = __builtin_amdgcn_mfma_f32_16x16x32_bf16(af0, bf0, acc[0][0], 0, 0, 0);
    acc[0][1] = __builtin_amdgcn_mfma_f32_16x16x32_bf16(af0, bf1, acc[0][1], 0, 0, 0);
    acc[1][0] = __builtin_amdgcn_mfma_f32_16x16x32_bf16(af1, bf0, acc[1][0], 0, 0, 0);
    acc[1][1] = __builtin_amdgcn_mfma_f32_16x16x32_bf16(af1, bf1, acc[1][1], 0, 0, 0);
  }
#pragma unroll
  for (int mi = 0; mi < 2; ++mi)
#pragma unroll
    for (int nj = 0; nj < 2; ++nj) {
      const int col = bn + wc + nj * 16 + l15;
      const float bcol = bias[col];
#pragma unroll
      for (int b = 0; b < 4; ++b) {
        const int row = bm + wr + mi * 16 + (lane >> 4) * 4 + b;
        float v = acc[mi][nj][b] + bcol;
        v = fmaxf(v, 0.f);
        O[(size_t)row * HID4 + col] = f2b(v);
      }
    }
}

// ------------------------------------------------------------------
// K10: per-sample wave: 640->1 and 640->4 dots + bbox combine
// ------------------------------------------------------------------
__global__ __launch_bounds__(256) void final_kernel(
    const ushort* __restrict__ hs, const ushort* __restrict__ hp,
    const float* __restrict__ ws4, const float* __restrict__ bs4,
    const float* __restrict__ wp4, const float* __restrict__ bp4,
    const float* __restrict__ pp, float* __restrict__ out, int N) {
  const int wid = threadIdx.x >> 6;
  const int lane = threadIdx.x & 63;
  const int n = blockIdx.x * 4 + wid;
  if (n >= N) return;
  const ushort* hsr = hs + (size_t)n * HID4;
  const ushort* hpr = hp + (size_t)n * HID4;
  float sc = 0.f, b0 = 0.f, b1 = 0.f, b2 = 0.f, b3 = 0.f;
  for (int j = lane; j < HID4; j += 64) {
    float h1 = b2f(hsr[j]);
    sc += h1 * ws4[j];
    float h2 = b2f(hpr[j]);
    b0 += h2 * wp4[j * 4 + 0];
    b1 += h2 * wp4[j * 4 + 1];
    b2 += h2 * wp4[j * 4 + 2];
    b3 += h2 * wp4[j * 4 + 3];
  }
  for (int off = 32; off > 0; off >>= 1) {
    sc += __shfl_down(sc, off);
    b0 += __shfl_down(b0, off);
    b1 += __shfl_down(b1, off);
    b2 += __shfl_down(b2, off);
    b3 += __shfl_down(b3, off);
  }
  if (lane == 0) {
    sc += bs4[0];
    b0 += bp4[0]; b1 += bp4[1]; b2 += bp4[2]; b3 += bp4[3];
    float so0 = fminf(fmaxf(b0, -2.f), 2.f);
    float so1 = fminf(fmaxf(b1, -2.f), 2.f);
    float po0 = fminf(fmaxf(b2, -2.f), 2.f);
    float po1 = fminf(fmaxf(b3, -2.f), 2.f);
    float px = pp[n * 4 + 0], py = pp[n * 4 + 1];
    float psx = pp[n * 4 + 2], psy = pp[n * 4 + 3];
    float wh0 = (psx + so0) * (1.f / 32.f);
    float wh1 = (psy + so1) * (1.f / 32.f);
    float xy0 = (px + po0) * (1.f / 32.f) - 0.5f * wh0;
    float xy1 = (py + po1) * (1.f / 32.f) - 0.5f * wh1;
    out[n * 4 + 0] = xy0;
    out[n * 4 + 1] = xy1;
    out[n * 4 + 2] = wh0;
    out[n * 4 + 3] = wh1;
    out[(size_t)4 * N + n] = sc;
  }
}

// ------------------------------------------------------------------
extern "C" void kernel_launch(void* const* d_in, const int* in_sizes, int n_in,
                              void* d_out, int out_size, void* d_ws, size_t ws_size,
                              hipStream_t stream) {
  const float* fpos = (const float*)d_in[0];
  const float* qemb = (const float*)d_in[1];
  const float* attn = (const float*)d_in[2];
  const float* ws1 = (const float*)d_in[3];
  const float* bs1 = (const float*)d_in[4];
  const float* ws2 = (const float*)d_in[5];
  const float* bs2 = (const float*)d_in[6];
  const float* ws3 = (const float*)d_in[7];
  const float* bs3 = (const float*)d_in[8];
  const float* ws4 = (const float*)d_in[9];
  const float* bs4 = (const float*)d_in[10];
  const float* wp1 = (const float*)d_in[11];
  const float* bp1 = (const float*)d_in[12];
  const float* wp2 = (const float*)d_in[13];
  const float* bp2 = (const float*)d_in[14];
  const float* wp3 = (const float*)d_in[15];
  const float* bp3 = (const float*)d_in[16];
  const float* wp4 = (const float*)d_in[17];
  const float* bp4 = (const float*)d_in[18];
  float* out = (float*)d_out;

  const int N = in_sizes[0] / (16 * HID);  // 4096

  char* ws = (char*)d_ws;
  const size_t SZ_QE = (size_t)N * HID * 2;        // 1,310,720
  const size_t SZ_W1 = (size_t)HID4 * HID * 2;     //   204,800
  const size_t SZ_W2 = (size_t)HID4 * HID4 * 2;    //   819,200
  const size_t SZ_H  = (size_t)N * HID4 * 2;       // 5,242,880
  size_t off = 0;
  ushort* qe_b = (ushort*)(ws + off); off += SZ_QE;
  ushort* fp_b = (ushort*)(ws + off); off += SZ_QE;
  ushort* wts1 = (ushort*)(ws + off); off += SZ_W1;
  ushort* wtp1 = (ushort*)(ws + off); off += SZ_W1;
  ushort* wts2 = (ushort*)(ws + off); off += SZ_W2;
  ushort* wtp2 = (ushort*)(ws + off); off += SZ_W2;
  ushort* wts3 = (ushort*)(ws + off); off += SZ_W2;
  ushort* wtp3 = (ushort*)(ws + off); off += SZ_W2;
  ushort* hsA  = (ushort*)(ws + off); off += SZ_H;
  ushort* hsB  = (ushort*)(ws + off); off += SZ_H;
  ushort* hpA  = (ushort*)(ws + off); off += SZ_H;
  ushort* hpB  = (ushort*)(ws + off); off += SZ_H;
  float*  pp   = (float*)(ws + off);  off += (size_t)N * 4 * 4;

  attn_kernel<<<N, 256, 0, stream>>>(attn, pp);

  const int total = N * HID;
  mean_kernel<<<(2 * total + 255) / 256, 256, 0, stream>>>(qemb, fpos, qe_b, fp_b, total);

  dim3 tb(32, 8);
  transpose_cast<<<dim3(HID4 / 32, HID / 32), tb, 0, stream>>>(ws1, wts1, HID);
  transpose_cast<<<dim3(HID4 / 32, HID / 32), tb, 0, stream>>>(wp1, wtp1, HID);
  transpose_cast<<<dim3(HID4 / 32, HID4 / 32), tb, 0, stream>>>(ws2, wts2, HID4);
  transpose_cast<<<dim3(HID4 / 32, HID4 / 32), tb, 0, stream>>>(wp2, wtp2, HID4);
  transpose_cast<<<dim3(HID4 / 32, HID4 / 32), tb, 0, stream>>>(ws3, wts3, HID4);
  transpose_cast<<<dim3(HID4 / 32, HID4 / 32), tb, 0, stream>>>(wp3, wtp3, HID4);

  dim3 gg(HID4 / 64, N / 64, 2);
  gemm_relu<HID><<<gg, 256, 0, stream>>>(qe_b, fp_b, wts1, wtp1, bs1, bp1, hsA, hpA);
  gemm_relu<HID4><<<gg, 256, 0, stream>>>(hsA, hpA, wts2, wtp2, bs2, bp2, hsB, hpB);
  gemm_relu<HID4><<<gg, 256, 0, stream>>>(hsB, hpB, wts3, wtp3, bs3, bp3, hsA, hpA);

  final_kernel<<<(N + 3) / 4, 256, 0, stream>>>(hsA, hpA, ws4, bs4, wp4, bp4, pp, out, N);
}

// Round 2
// 119.356 us; speedup vs baseline: 1.2139x; 1.2139x over previous
//
#include <hip/hip_runtime.h>
#include <hip/hip_bf16.h>
#include <stdint.h>

#define HID 160
#define HID4 640
#define FDIM 32
#define NPIX 1024

// Gaussian blur taps: e = exp(-0.5); k = [e,1,e]/(1+2e)
#define GK0 0.27406862f
#define GK1 0.45186276f

typedef __attribute__((ext_vector_type(8))) short short8;
typedef __attribute__((ext_vector_type(4))) float f32x4;

__device__ __forceinline__ ushort f2b(float f) {
  union { float f; uint32_t u; } v; v.f = f;
  uint32_t u = v.u;
  u += 0x7fffu + ((u >> 16) & 1u);   // RNE
  return (ushort)(u >> 16);
}
__device__ __forceinline__ float b2f(ushort s) {
  union { uint32_t u; float f; } v; v.u = ((uint32_t)s) << 16;
  return v.f;
}

// async global->LDS, 16B per lane; LDS dest = wave-uniform base + lane*16
__device__ __forceinline__ void gload16(const ushort* g, ushort* l) {
  __builtin_amdgcn_global_load_lds(
      (const __attribute__((address_space(1))) void*)g,
      (__attribute__((address_space(3))) void*)l, 16, 0, 0);
}

// ------------------------------------------------------------------
// Shared-memory union: GEMM tiles and attn scratch never coexist
// ------------------------------------------------------------------
union SMem {
  struct {
    ushort la[128 * 32];   // 8 KB, linear (global_load_lds requirement)
    ushort lb[128 * 32];   // 8 KB
  } g;
  struct {
    float am[FDIM][FDIM + 1];
    float tmp[FDIM][FDIM + 1];
    float bl[FDIM][FDIM + 1];
    float rowsum[FDIM], colsum[FDIM];
    float redv[4];
    int redi[4];
  } a;
};

// ------------------------------------------------------------------
// attn per-sample processing (block role inside gemm_attn)
// ------------------------------------------------------------------
__device__ void attn_block(SMem& sm, const float* __restrict__ attn,
                           float* __restrict__ pp, int n) {
  const int tid = threadIdx.x;
  const float* base = attn + (size_t)n * (16 * NPIX);
  float4 a = make_float4(0.f, 0.f, 0.f, 0.f);
#pragma unroll
  for (int q = 0; q < 16; ++q) {
    float4 v = *(const float4*)(base + q * NPIX + tid * 4);
    a.x += v.x; a.y += v.y; a.z += v.z; a.w += v.w;
  }
  {
    const int f0 = tid * 4;
    const int r = f0 >> 5, c = f0 & 31;
    sm.a.am[r][c + 0] = a.x * 0.0625f;
    sm.a.am[r][c + 1] = a.y * 0.0625f;
    sm.a.am[r][c + 2] = a.z * 0.0625f;
    sm.a.am[r][c + 3] = a.w * 0.0625f;
  }
  __syncthreads();
  for (int f = tid; f < NPIX; f += 256) {
    int r = f >> 5, c = f & 31;
    int rm = (r == 0) ? 1 : r - 1;
    int rp = (r == 31) ? 30 : r + 1;
    sm.a.tmp[r][c] = GK0 * sm.a.am[rm][c] + GK1 * sm.a.am[r][c] + GK0 * sm.a.am[rp][c];
  }
  __syncthreads();
  for (int f = tid; f < NPIX; f += 256) {
    int r = f >> 5, c = f & 31;
    int cm = (c == 0) ? 1 : c - 1;
    int cp = (c == 31) ? 30 : c + 1;
    sm.a.bl[r][c] = GK0 * sm.a.tmp[r][cm] + GK1 * sm.a.tmp[r][c] + GK0 * sm.a.tmp[r][cp];
  }
  __syncthreads();
  // argmax of blurred map (normalization is affine+positive => argmax-invariant)
  float bv = -1e30f; int bi = 0;
  for (int f = tid; f < NPIX; f += 256) {
    float v = sm.a.bl[f >> 5][f & 31];
    if (v > bv || (v == bv && f < bi)) { bv = v; bi = f; }
  }
  for (int off = 32; off > 0; off >>= 1) {
    float ov = __shfl_down(bv, off);
    int oi = __shfl_down(bi, off);
    if (ov > bv || (ov == bv && oi < bi)) { bv = ov; bi = oi; }
  }
  if ((tid & 63) == 0) { sm.a.redv[tid >> 6] = bv; sm.a.redi[tid >> 6] = bi; }
  for (int f = tid; f < NPIX; f += 256) {
    int r = f >> 5, c = f & 31;
    float s = 1.f / (1.f + expf(-sm.a.am[r][c]));
    sm.a.tmp[r][c] = fminf(fmaxf(s, 1e-4f), 0.9999f);
  }
  __syncthreads();
  if (tid < 32) {
    float s = 0.f;
    for (int c = 0; c < 32; ++c) s += sm.a.tmp[tid][c];
    sm.a.rowsum[tid] = s;
  } else if (tid < 64) {
    int c = tid - 32;
    float s = 0.f;
    for (int r = 0; r < 32; ++r) s += sm.a.tmp[r][c];
    sm.a.colsum[c] = s;
  }
  __syncthreads();
  if (tid == 0) {
    float bestv = sm.a.redv[0]; int besti = sm.a.redi[0];
    for (int w = 1; w < 4; ++w)
      if (sm.a.redv[w] > bestv || (sm.a.redv[w] == bestv && sm.a.redi[w] < besti)) {
        bestv = sm.a.redv[w]; besti = sm.a.redi[w];
      }
    int px = besti & 31, py = besti >> 5;
    int c0 = max(0, px - 3), c1 = min(32, px + 3);
    float sx = 0.f;
    for (int c = c0; c < c1; ++c) sx += sm.a.colsum[c];
    float psx = (sx / (32.f * (float)(c1 - c0))) * 32.f;
    int r0 = max(0, py - 3), r1 = min(32, py + 3);
    float sy = 0.f;
    for (int r = r0; r < r1; ++r) sy += sm.a.rowsum[r];
    float psy = (sy / (32.f * (float)(r1 - r0))) * 32.f;
    pp[n * 4 + 0] = (float)px;
    pp[n * 4 + 1] = (float)py;
    pp[n * 4 + 2] = psx;
    pp[n * 4 + 3] = psy;
  }
}

// ------------------------------------------------------------------
// Fused: 128x128-tile MFMA GEMM (m97 structure: global_load_lds w16,
// BK=32, 4 waves x 4x4 frags) + attn sample blocks in the same grid.
// ------------------------------------------------------------------
template <int K>
__global__ __launch_bounds__(256) void gemm_attn(
    const ushort* __restrict__ A0, const ushort* __restrict__ A1,
    const ushort* __restrict__ W0, const ushort* __restrict__ W1,
    const float* __restrict__ B0, const float* __restrict__ B1,
    ushort* __restrict__ O0, ushort* __restrict__ O1,
    const float* __restrict__ attn, float* __restrict__ pp,
    int attn_base, int n_gemm) {
  __shared__ SMem sm;
  const int tid = threadIdx.x;

  if ((int)blockIdx.x >= n_gemm) {
    attn_block(sm, attn, pp, attn_base + (int)blockIdx.x - n_gemm);
    return;
  }

  const int bid = blockIdx.x;
  const int half = n_gemm >> 1;
  const int chain = bid >= half;
  const int r = chain ? bid - half : bid;
  const int bn = (r % 5) * 128;
  const int bm = (r / 5) * 128;
  const ushort* A = chain ? A1 : A0;
  const ushort* W = chain ? W1 : W0;
  const float* bias = chain ? B1 : B0;
  ushort* O = chain ? O1 : O0;

  const int lane = tid & 63;
  const int wid = tid >> 6;
  const int wr = (wid >> 1) * 64;
  const int wc = (wid & 1) * 64;
  const int l15 = lane & 15;
  const int kq = (lane >> 4) * 8;

  const int rstage = tid >> 2;         // 0..63 (row within 64-row half)
  const int cstage = (tid & 3) * 8;    // k-seg 0,8,16,24
  ushort* la = sm.g.la;
  ushort* lb = sm.g.lb;
  const int ldsbase = wid * 512;       // wave-uniform elem offset, lane adds *8

  f32x4 acc[4][4] = {};
  for (int k0 = 0; k0 < K; k0 += 32) {
#pragma unroll
    for (int j = 0; j < 2; ++j) {
      gload16(A + (size_t)(bm + j * 64 + rstage) * K + k0 + cstage,
              la + j * 2048 + ldsbase);
      gload16(W + (size_t)(bn + j * 64 + rstage) * K + k0 + cstage,
              lb + j * 2048 + ldsbase);
    }
    __syncthreads();   // vmcnt(0) + barrier: tiles ready
    short8 af[4], bf[4];
#pragma unroll
    for (int i = 0; i < 4; ++i) {
      af[i] = *(const short8*)(la + (wr + i * 16 + l15) * 32 + kq);
      bf[i] = *(const short8*)(lb + (wc + i * 16 + l15) * 32 + kq);
    }
#pragma unroll
    for (int mi = 0; mi < 4; ++mi)
#pragma unroll
      for (int nj = 0; nj < 4; ++nj)
        acc[mi][nj] = __builtin_amdgcn_mfma_f32_16x16x32_bf16(af[mi], bf[nj], acc[mi][nj], 0, 0, 0);
    __syncthreads();   // protect tiles before next overwrite
  }

#pragma unroll
  for (int nj = 0; nj < 4; ++nj) {
    const int col = bn + wc + nj * 16 + l15;
    const float bcol = bias[col];
#pragma unroll
    for (int mi = 0; mi < 4; ++mi) {
      const int rbase = bm + wr + mi * 16 + (lane >> 4) * 4;
#pragma unroll
      for (int b = 0; b < 4; ++b) {
        float v = acc[mi][nj][b] + bcol;
        O[(size_t)(rbase + b) * HID4 + col] = f2b(fmaxf(v, 0.f));
      }
    }
  }
}

// ------------------------------------------------------------------
// prep: mean-over-Q (+bf16 cast) for qe/fp, plus all 6 weight
// transpose+cast jobs, one launch (block roles).
// ------------------------------------------------------------------
__global__ __launch_bounds__(256) void prep_kernel(
    const float* __restrict__ qemb, const float* __restrict__ fpos,
    ushort* __restrict__ qe_b, ushort* __restrict__ fp_b,
    const float* __restrict__ ws1, ushort* __restrict__ wts1,
    const float* __restrict__ wp1, ushort* __restrict__ wtp1,
    const float* __restrict__ ws2, ushort* __restrict__ wts2,
    const float* __restrict__ wp2, ushort* __restrict__ wtp2,
    const float* __restrict__ ws3, ushort* __restrict__ wts3,
    const float* __restrict__ wp3, ushort* __restrict__ wtp3,
    int n_mean_blocks, int total) {
  const int tid = threadIdx.x;
  const int bid = blockIdx.x;

  if (bid < n_mean_blocks) {
    // each thread: one float2 pair (16 strided float2 loads)
    int idx = bid * 256 + tid;
    const int pairs = total >> 1;
    const float* src; ushort* dst; int i;
    if (idx < pairs) { src = qemb; dst = qe_b; i = idx; }
    else             { src = fpos; dst = fp_b; i = idx - pairs; }
    int nn = i / (HID / 2);
    int h = (i - nn * (HID / 2)) * 2;
    const float* p = src + (size_t)nn * (16 * HID) + h;
    float sx = 0.f, sy = 0.f;
#pragma unroll
    for (int q = 0; q < 16; ++q) {
      float2 v = *(const float2*)(p + q * HID);
      sx += v.x; sy += v.y;
    }
    ushort2 o;
    o.x = f2b(sx * 0.0625f);
    o.y = f2b(sy * 0.0625f);
    *(ushort2*)(dst + (size_t)nn * HID + h) = o;
    return;
  }

  // transpose roles
  int r = bid - n_mean_blocks;
  const float* in; ushort* out; int K;
  if (r < 100)       { in = ws1; out = wts1; K = HID; }
  else if (r < 200)  { in = wp1; out = wtp1; K = HID; r -= 100; }
  else if (r < 600)  { in = ws2; out = wts2; K = HID4; r -= 200; }
  else if (r < 1000) { in = wp2; out = wtp2; K = HID4; r -= 600; }
  else if (r < 1400) { in = ws3; out = wts3; K = HID4; r -= 1000; }
  else               { in = wp3; out = wtp3; K = HID4; r -= 1400; }
  const int bx = (r % 20) * 32;   // n base
  const int by = (r / 20) * 32;   // k base
  const int lx = tid & 31;
  const int ly = tid >> 5;
  __shared__ float t[32][33];
#pragma unroll
  for (int i = 0; i < 4; ++i)
    t[ly + i * 8][lx] = in[(size_t)(by + ly + i * 8) * HID4 + bx + lx];
  __syncthreads();
#pragma unroll
  for (int i = 0; i < 4; ++i)
    out[(size_t)(bx + ly + i * 8) * K + by + lx] = f2b(t[lx][ly + i * 8]);
}

// ------------------------------------------------------------------
// final: 640->1 and 640->4 dots per sample (one wave each) + combine
// ------------------------------------------------------------------
__global__ __launch_bounds__(256) void final_kernel(
    const ushort* __restrict__ hs, const ushort* __restrict__ hp,
    const float* __restrict__ ws4, const float* __restrict__ bs4,
    const float* __restrict__ wp4, const float* __restrict__ bp4,
    const float* __restrict__ pp, float* __restrict__ out, int N) {
  const int wid = threadIdx.x >> 6;
  const int lane = threadIdx.x & 63;
  const int n = blockIdx.x * 4 + wid;
  if (n >= N) return;
  const ushort* hsr = hs + (size_t)n * HID4;
  const ushort* hpr = hp + (size_t)n * HID4;
  float sc = 0.f, b0 = 0.f, b1 = 0.f, b2 = 0.f, b3 = 0.f;
  for (int j = lane; j < HID4; j += 64) {
    float h1 = b2f(hsr[j]);
    sc += h1 * ws4[j];
    float h2 = b2f(hpr[j]);
    b0 += h2 * wp4[j * 4 + 0];
    b1 += h2 * wp4[j * 4 + 1];
    b2 += h2 * wp4[j * 4 + 2];
    b3 += h2 * wp4[j * 4 + 3];
  }
  for (int off = 32; off > 0; off >>= 1) {
    sc += __shfl_down(sc, off);
    b0 += __shfl_down(b0, off);
    b1 += __shfl_down(b1, off);
    b2 += __shfl_down(b2, off);
    b3 += __shfl_down(b3, off);
  }
  if (lane == 0) {
    sc += bs4[0];
    b0 += bp4[0]; b1 += bp4[1]; b2 += bp4[2]; b3 += bp4[3];
    float so0 = fminf(fmaxf(b0, -2.f), 2.f);
    float so1 = fminf(fmaxf(b1, -2.f), 2.f);
    float po0 = fminf(fmaxf(b2, -2.f), 2.f);
    float po1 = fminf(fmaxf(b3, -2.f), 2.f);
    float px = pp[n * 4 + 0], py = pp[n * 4 + 1];
    float psx = pp[n * 4 + 2], psy = pp[n * 4 + 3];
    float wh0 = (psx + so0) * (1.f / 32.f);
    float wh1 = (psy + so1) * (1.f / 32.f);
    float xy0 = (px + po0) * (1.f / 32.f) - 0.5f * wh0;
    float xy1 = (py + po1) * (1.f / 32.f) - 0.5f * wh1;
    out[n * 4 + 0] = xy0;
    out[n * 4 + 1] = xy1;
    out[n * 4 + 2] = wh0;
    out[n * 4 + 3] = wh1;
    out[(size_t)4 * N + n] = sc;
  }
}

// ------------------------------------------------------------------
extern "C" void kernel_launch(void* const* d_in, const int* in_sizes, int n_in,
                              void* d_out, int out_size, void* d_ws, size_t ws_size,
                              hipStream_t stream) {
  const float* fpos = (const float*)d_in[0];
  const float* qemb = (const float*)d_in[1];
  const float* attn = (const float*)d_in[2];
  const float* ws1 = (const float*)d_in[3];
  const float* bs1 = (const float*)d_in[4];
  const float* ws2 = (const float*)d_in[5];
  const float* bs2 = (const float*)d_in[6];
  const float* ws3 = (const float*)d_in[7];
  const float* bs3 = (const float*)d_in[8];
  const float* ws4 = (const float*)d_in[9];
  const float* bs4 = (const float*)d_in[10];
  const float* wp1 = (const float*)d_in[11];
  const float* bp1 = (const float*)d_in[12];
  const float* wp2 = (const float*)d_in[13];
  const float* bp2 = (const float*)d_in[14];
  const float* wp3 = (const float*)d_in[15];
  const float* bp3 = (const float*)d_in[16];
  const float* wp4 = (const float*)d_in[17];
  const float* bp4 = (const float*)d_in[18];
  float* out = (float*)d_out;

  const int N = in_sizes[0] / (16 * HID);  // 4096

  char* ws = (char*)d_ws;
  const size_t SZ_QE = (size_t)N * HID * 2;
  const size_t SZ_W1 = (size_t)HID4 * HID * 2;
  const size_t SZ_W2 = (size_t)HID4 * HID4 * 2;
  const size_t SZ_H  = (size_t)N * HID4 * 2;
  size_t off = 0;
  ushort* qe_b = (ushort*)(ws + off); off += SZ_QE;
  ushort* fp_b = (ushort*)(ws + off); off += SZ_QE;
  ushort* wts1 = (ushort*)(ws + off); off += SZ_W1;
  ushort* wtp1 = (ushort*)(ws + off); off += SZ_W1;
  ushort* wts2 = (ushort*)(ws + off); off += SZ_W2;
  ushort* wtp2 = (ushort*)(ws + off); off += SZ_W2;
  ushort* wts3 = (ushort*)(ws + off); off += SZ_W2;
  ushort* wtp3 = (ushort*)(ws + off); off += SZ_W2;
  ushort* hsA  = (ushort*)(ws + off); off += SZ_H;
  ushort* hsB  = (ushort*)(ws + off); off += SZ_H;
  ushort* hpA  = (ushort*)(ws + off); off += SZ_H;
  ushort* hpB  = (ushort*)(ws + off); off += SZ_H;
  float*  pp   = (float*)(ws + off);  off += (size_t)N * 4 * 4;

  // prep: means (+cast) and the 6 weight transposes, one launch
  const int total = N * HID;
  const int n_mean_blocks = (2 * (total >> 1) + 255) / 256;   // 2560 for N=4096
  prep_kernel<<<n_mean_blocks + 1800, 256, 0, stream>>>(
      qemb, fpos, qe_b, fp_b, ws1, wts1, wp1, wtp1, ws2, wts2, wp2, wtp2,
      ws3, wts3, wp3, wtp3, n_mean_blocks, total);

  // GEMM grid per launch: 2 chains x 5 n-blocks x (N/128) m-blocks
  const int n_gemm = 2 * 5 * (N / 128);   // 320
  // attn split across 3 launches: gemm1 is short -> biggest chunk
  const int a2 = (N * 29) / 100;
  const int a3 = a2;
  const int a1 = N - a2 - a3;

  gemm_attn<HID><<<n_gemm + a1, 256, 0, stream>>>(
      qe_b, fp_b, wts1, wtp1, bs1, bp1, hsA, hpA, attn, pp, 0, n_gemm);
  gemm_attn<HID4><<<n_gemm + a2, 256, 0, stream>>>(
      hsA, hpA, wts2, wtp2, bs2, bp2, hsB, hpB, attn, pp, a1, n_gemm);
  gemm_attn<HID4><<<n_gemm + a3, 256, 0, stream>>>(
      hsB, hpB, wts3, wtp3, bs3, bp3, hsA, hpA, attn, pp, a1 + a2, n_gemm);

  final_kernel<<<(N + 3) / 4, 256, 0, stream>>>(hsA, hpA, ws4, bs4, wp4, bp4, pp, out, N);
}